// Round 3
// baseline (80023.212 us; speedup 1.0000x reference)
//
#include <hip/hip_runtime.h>

// GRU persistent kernel, round 3: self-validating XCD-local comm with fallback.
//
// Data plane (proven in round 1): h broadcast as tagged 8B words (value|step),
// packed 2-per-16B line, double-buffered by step parity; LDS fan-out per WG;
// weight_hh register-resident; igates fused, prefetched 1 step ahead.
//
// Placement: WGs claim slots per physical XCD (HW_REG_XCC_ID). Each would-be
// replica SMOKE-TESTS its own coherence (sc0 store -> sc0 poll, two rounds to
// defeat stale-L1 false passes), then commits unanimously via an ok-counter
// rendezvous. Committed replicas run redundantly (bit-identical output).
// Any failure -> WGs defect to a global-mode replica using sc0+sc1 (system
// scope) ops, the round-1-proven path. All spins guarded; worst case is a
// fast wrong-answer, never a hang.

#define T_STEPS    32768
#define INSZ       256
#define HSZ        512
#define TPB        256
#define NWG_RUN    32
#define NWG_LAUNCH 256
#define POLL_GUARD 8192
#define SMOKE_GUARD (1 << 16)
#define WAIT_GUARD  (1 << 16)

typedef unsigned long long u64;
typedef unsigned int u32;
typedef u32 u32x4 __attribute__((ext_vector_type(4)));
typedef float f32x4 __attribute__((ext_vector_type(4)));

// ---- scoped comm ops: SYS=0 -> sc0 (L1-bypass, XCD-L2 served);
// ----                  SYS=1 -> sc0 sc1 (coherent-point served, device-wide)
template<int SYS> __device__ __forceinline__ u32x4 ld16(const u64* p) {
  u32x4 v;
  if constexpr (SYS) asm volatile("global_load_dwordx4 %0, %1, off sc0 sc1\n\ts_waitcnt vmcnt(0)" : "=v"(v) : "v"(p) : "memory");
  else               asm volatile("global_load_dwordx4 %0, %1, off sc0\n\ts_waitcnt vmcnt(0)"     : "=v"(v) : "v"(p) : "memory");
  return v;
}
template<int SYS> __device__ __forceinline__ void st16(u64* p, u32x4 v) {
  if constexpr (SYS) asm volatile("global_store_dwordx4 %0, %1, off sc0 sc1" :: "v"(p), "v"(v) : "memory");
  else               asm volatile("global_store_dwordx4 %0, %1, off sc0"     :: "v"(p), "v"(v) : "memory");
}
template<int SYS> __device__ __forceinline__ u32 ldw(const u32* p) {
  u32 v;
  if constexpr (SYS) asm volatile("global_load_dword %0, %1, off sc0 sc1\n\ts_waitcnt vmcnt(0)" : "=v"(v) : "v"(p) : "memory");
  else               asm volatile("global_load_dword %0, %1, off sc0\n\ts_waitcnt vmcnt(0)"     : "=v"(v) : "v"(p) : "memory");
  return v;
}
template<int SYS> __device__ __forceinline__ void stw(u32* p, u32 v) {
  if constexpr (SYS) asm volatile("global_store_dword %0, %1, off sc0 sc1" :: "v"(p), "v"(v) : "memory");
  else               asm volatile("global_store_dword %0, %1, off sc0"     :: "v"(p), "v"(v) : "memory");
}

__device__ __forceinline__ int wait_ge_sys(const u32* p, u32 target, int guard) {
  while (guard-- > 0) { if (ldw<1>(p) >= target) return 1; }
  return 0;
}

__device__ __forceinline__ float grp_reduce16(float v) {
  v += __shfl_xor(v, 1);
  v += __shfl_xor(v, 2);
  v += __shfl_xor(v, 4);
  v += __shfl_xor(v, 8);
  return v;
}

// LDS pad: +4 floats per 32 (float4-aligned, breaks stride-32 bank alias)
__device__ __forceinline__ int hpad(int k) { return k + 4 * (k >> 5); }

// Re-init every call (harness does not re-poison d_ws between graph replays).
__global__ void init_comm(u64* __restrict__ comm, u32* __restrict__ ctrl,
                          u32* __restrict__ smoke, const float* __restrict__ h0) {
  int jj = threadIdx.x;                       // 0..511
  u32 bits = __float_as_uint(h0[jj]);
  #pragma unroll
  for (int r = 0; r < 9; ++r) {
    comm[r * 1024 + jj]       = (u64)bits;               // buf0: tag 0 | h0
    comm[r * 1024 + 512 + jj] = 0xFFFFFFFF00000000ull;   // buf1: invalid tag
  }
  if (jj < 32)  ctrl[jj]  = 0;   // [0..7]=claims/XCD, [8..15]=smoke-ok/XCD, [16]=global bids
  if (jj < 256) smoke[jj] = 0;
}

template<int SYS>
__device__ void run_gru(const float* __restrict__ input,
                        const float* __restrict__ w_ih,
                        const float* __restrict__ w_hh,
                        const float* __restrict__ bias,
                        const float* __restrict__ bias_n,
                        u64* __restrict__ comm,
                        float* __restrict__ out, int wg, int tid)
{
  const int g      = tid >> 4;
  const int l      = tid & 15;
  const int laneid = tid & 63;
  const int j      = wg * 16 + g;

  // w_hh rows register-resident (96 VGPR); w_ih stays cache-sourced (off path)
  f32x4 whh[3][8];
  #pragma unroll
  for (int q = 0; q < 3; ++q) {
    const float* rp = w_hh + (size_t)(j + 512 * q) * HSZ + l * 32;
    #pragma unroll
    for (int c = 0; c < 8; ++c) whh[q][c] = *(const f32x4*)(rp + c * 4);
  }
  const float b_r = bias[j], b_z = bias[j + 512], b_n = bias[j + 1024];
  const float bn2 = bias_n[j];
  const float* wp0 = w_ih + (size_t)j * INSZ + l * 16;
  const float* wp1 = wp0 + (size_t)512 * INSZ;
  const float* wp2 = wp1 + (size_t)512 * INSZ;

  __shared__ float h_lds[HSZ + 4 * (HSZ >> 5)];

  // igates for step 0
  float ig0, ig1, ig2;
  {
    const float* ip = input + l * 16;
    f32x4 x0 = *(const f32x4*)(ip + 0);
    f32x4 x1 = *(const f32x4*)(ip + 4);
    f32x4 x2 = *(const f32x4*)(ip + 8);
    f32x4 x3 = *(const f32x4*)(ip + 12);
    float a0 = 0.f, a1 = 0.f, a2 = 0.f;
    #pragma unroll
    for (int c = 0; c < 4; ++c) {
      f32x4 w0 = *(const f32x4*)(wp0 + c * 4);
      f32x4 w1 = *(const f32x4*)(wp1 + c * 4);
      f32x4 w2 = *(const f32x4*)(wp2 + c * 4);
      f32x4 xv = (c == 0) ? x0 : ((c == 1) ? x1 : ((c == 2) ? x2 : x3));
      #pragma unroll
      for (int u = 0; u < 4; ++u) {
        a0 += w0[u] * xv[u]; a1 += w1[u] * xv[u]; a2 += w2[u] * xv[u];
      }
    }
    ig0 = grp_reduce16(a0); ig1 = grp_reduce16(a1); ig2 = grp_reduce16(a2);
  }

  for (int t = 0; t < T_STEPS; ++t) {
    const u64* buf = comm + (size_t)(t & 1) * HSZ;
    const u32 tt = (u32)t;

    // poll h_t: each thread owns one 16B line = words {2tid, 2tid+1}
    const u64* lp = buf + 2 * tid;
    u32x4 v;
    int guard = POLL_GUARD;
    for (;;) {
      v = ld16<SYS>(lp);
      if ((v.y == tt && v.w == tt) || --guard == 0) break;
    }
    h_lds[hpad(2 * tid)]     = __uint_as_float(v.x);
    h_lds[hpad(2 * tid + 1)] = __uint_as_float(v.z);
    __syncthreads();

    // issue next input row early (latency hidden under matvec)
    const int tn = (t + 1 < T_STEPS) ? (t + 1) : (T_STEPS - 1);
    const float* ipn = input + (size_t)tn * INSZ + l * 16;
    f32x4 nv0 = *(const f32x4*)(ipn + 0);
    f32x4 nv1 = *(const f32x4*)(ipn + 4);
    f32x4 nv2 = *(const f32x4*)(ipn + 8);
    f32x4 nv3 = *(const f32x4*)(ipn + 12);

    // hh matvec (critical path)
    float hr = 0.f, hz = 0.f, hn = 0.f;
    const float* hp = &h_lds[l * 36];   // hpad(l*32)
    #pragma unroll
    for (int c = 0; c < 8; ++c) {
      f32x4 hv = *(const f32x4*)(hp + c * 4);
      #pragma unroll
      for (int u = 0; u < 4; ++u) {
        hr += whh[0][c][u] * hv[u];
        hz += whh[1][c][u] * hv[u];
        hn += whh[2][c][u] * hv[u];
      }
    }
    hr = grp_reduce16(hr); hz = grp_reduce16(hz); hn = grp_reduce16(hn);

    // round-1-proven gate math (absmax 9.8e-4)
    const float reset = 1.0f / (1.0f + __expf(-(ig0 + b_r + hr)));
    const float upd   = 1.0f / (1.0f + __expf(-(ig1 + b_z + hz)));
    const float hold  = h_lds[hpad(j)];
    const float newv  = tanhf(ig2 + b_n + reset * (hn + bn2));
    const float hnew  = newv + upd * (hold - newv);

    // broadcast: 2 tagged words per 16B line, one store per even group
    const float hpart = __shfl(hnew, (laneid + 16) & 63);
    if (l == 0 && (g & 1) == 0) {
      u64* nbuf = comm + (size_t)((t + 1) & 1) * HSZ;
      u32x4 pk;
      pk.x = __float_as_uint(hnew);  pk.y = (u32)(t + 1);
      pk.z = __float_as_uint(hpart); pk.w = (u32)(t + 1);
      st16<SYS>(&nbuf[j], pk);
      if (j == 0) out[t] = hnew;
    }

    // igates for step t+1 (off critical path; w_ih from cache)
    {
      float a0 = 0.f, a1 = 0.f, a2 = 0.f;
      #pragma unroll
      for (int c = 0; c < 4; ++c) {
        f32x4 w0 = *(const f32x4*)(wp0 + c * 4);
        f32x4 w1 = *(const f32x4*)(wp1 + c * 4);
        f32x4 w2 = *(const f32x4*)(wp2 + c * 4);
        f32x4 xv = (c == 0) ? nv0 : ((c == 1) ? nv1 : ((c == 2) ? nv2 : nv3));
        #pragma unroll
        for (int u = 0; u < 4; ++u) {
          a0 += w0[u] * xv[u]; a1 += w1[u] * xv[u]; a2 += w2[u] * xv[u];
        }
      }
      ig0 = grp_reduce16(a0); ig1 = grp_reduce16(a1); ig2 = grp_reduce16(a2);
    }
    __syncthreads();   // protect h_lds before next iteration's fill
  }

  // keep-alive: pin whh residency across the loop (defeats rematerialization)
  asm volatile("" ::
    "v"(whh[0][0]), "v"(whh[0][1]), "v"(whh[0][2]), "v"(whh[0][3]),
    "v"(whh[0][4]), "v"(whh[0][5]), "v"(whh[0][6]), "v"(whh[0][7]),
    "v"(whh[1][0]), "v"(whh[1][1]), "v"(whh[1][2]), "v"(whh[1][3]),
    "v"(whh[1][4]), "v"(whh[1][5]), "v"(whh[1][6]), "v"(whh[1][7]),
    "v"(whh[2][0]), "v"(whh[2][1]), "v"(whh[2][2]), "v"(whh[2][3]),
    "v"(whh[2][4]), "v"(whh[2][5]), "v"(whh[2][6]), "v"(whh[2][7]));
}

__launch_bounds__(TPB, 1)
__global__ void gru_persistent(const float* __restrict__ input,
                               const float* __restrict__ w_ih,
                               const float* __restrict__ w_hh,
                               const float* __restrict__ bias,
                               const float* __restrict__ bias_n,
                               u64* __restrict__ comm,
                               u32* __restrict__ ctrl,
                               u32* __restrict__ smoke,
                               float* __restrict__ out)
{
  const int tid = threadIdx.x;
  __shared__ int s_rep, s_slot, s_res, s_fail;

  // ---- claim a slot on my physical XCD ----
  if (tid == 0) {
    u32 xcd;
    asm volatile("s_getreg_b32 %0, hwreg(HW_REG_XCC_ID)" : "=s"(xcd));
    s_rep  = (int)(xcd & 7);
    s_slot = (int)atomicAdd(&ctrl[xcd & 7], 1u);   // device-scope
  }
  __syncthreads();
  int rep = s_rep, slot = s_slot;
  int mode = 0;   // 0=exit, 1=xcd-local, 2=global fallback

  if (slot < NWG_RUN) {
    u32* sm = smoke + rep * 32;
    const int w = tid & 31;
    // ---- smoke round A: every member stores, everyone polls all 32 words ----
    if (tid == 0) { s_fail = 0; stw<0>(&sm[slot], 0xA5000000u | (u32)slot); }
    __syncthreads();
    {
      const u32 ea = 0xA5000000u | (u32)w, eb = 0xB6000000u | (u32)w;
      int gd = SMOKE_GUARD, good = 0;
      while (gd-- > 0) { u32 x = ldw<0>(&sm[w]); if (x == ea || x == eb) { good = 1; break; } }
      if (!good) atomicAdd(&s_fail, 1);
    }
    __syncthreads();
    if (s_fail == 0) {
      // ---- smoke round B: rewrite same words; stale-L1 caching would fail here
      if (tid == 0) stw<0>(&sm[slot], 0xB6000000u | (u32)slot);
      __syncthreads();
      {
        const u32 eb = 0xB6000000u | (u32)w;
        int gd = SMOKE_GUARD, good = 0;
        while (gd-- > 0) { u32 x = ldw<0>(&sm[w]); if (x == eb) { good = 1; break; } }
        if (!good) atomicAdd(&s_fail, 1);
      }
      __syncthreads();
      if (s_fail == 0) {
        // ---- unanimous commit rendezvous ----
        if (tid == 0) {
          atomicAdd(&ctrl[8 + rep], 1u);
          s_res = wait_ge_sys(&ctrl[8 + rep], NWG_RUN, WAIT_GUARD);
        }
        __syncthreads();
        if (s_res) mode = 1;
      }
    }
  }

  if (mode == 0) {
    // ---- global fallback bid (round-1-proven system-scope path) ----
    if (tid == 0) {
      int gb = (int)atomicAdd(&ctrl[16], 1u);
      s_slot = gb;
      s_res = (gb < NWG_RUN) ? wait_ge_sys(&ctrl[16], NWG_RUN, WAIT_GUARD) : 0;
    }
    __syncthreads();
    if (s_res) { mode = 2; rep = 8; slot = s_slot; }
  }
  if (mode == 0) return;

  u64* mycomm = comm + (size_t)rep * 1024;
  if (mode == 1) run_gru<0>(input, w_ih, w_hh, bias, bias_n, mycomm, out, slot, tid);
  else           run_gru<1>(input, w_ih, w_hh, bias, bias_n, mycomm, out, slot, tid);
}

extern "C" void kernel_launch(void* const* d_in, const int* in_sizes, int n_in,
                              void* d_out, int out_size, void* d_ws, size_t ws_size,
                              hipStream_t stream) {
  const float* input  = (const float*)d_in[0];
  const float* h0     = (const float*)d_in[1];
  const float* w_ih   = (const float*)d_in[2];
  const float* w_hh   = (const float*)d_in[3];
  const float* bias   = (const float*)d_in[4];
  const float* bias_n = (const float*)d_in[5];
  float* out = (float*)d_out;
  u64* comm  = (u64*)d_ws;                               // 9 replicas * 8 KB
  u32* ctrl  = (u32*)((char*)d_ws + 9 * 1024 * 8);       // 32 u32
  u32* smoke = ctrl + 32;                                // 8 * 32 u32

  hipLaunchKernelGGL(init_comm, dim3(1), dim3(HSZ), 0, stream, comm, ctrl, smoke, h0);
  hipLaunchKernelGGL(gru_persistent, dim3(NWG_LAUNCH), dim3(TPB), 0, stream,
                     input, w_ih, w_hh, bias, bias_n, comm, ctrl, smoke, out);
}

// Round 5
// 62666.394 us; speedup vs baseline: 1.2770x; 1.2770x over previous
//
#include <hip/hip_runtime.h>

// GRU persistent kernel, round 5: simple device-scope comm, engineered latency.
// - 16 WGs x 512 threads. Each WG owns 32 h-rows (16 lanes/row).
// - h broadcast: tagged 8B words {val|step}, 2 per 16B line, double-buffered
//   by step parity (round-1-proven protocol; max skew 1 step => race-free).
// - 4-deep pipelined tag polling (s_waitcnt vmcnt(3) ring): detect quantum
//   ~latency/4 instead of a full serialized round trip per miss.
// - w_hh AND w_ih pinned register-resident via in-loop "+v" asm (round-3
//   VGPR=112 proved the compiler remats weight loads without this).
// - Parity-indexed LDS h buffer -> single __syncthreads per step.
// - No placement protocol, no smoke tests, no fallback: nothing can hang;
//   poll guard turns comm failure into a fast wrong-answer, never a timeout.

#define T_STEPS    32768
#define INSZ       256
#define HSZ        512
#define TPB        512
#define NWG        16
#define SWG        32          // h rows per WG
#define POLL_GUARD 16384       // per-check; worst case ~10s then absmax-fail

typedef unsigned long long u64;
typedef unsigned int u32;
typedef u32 u32x4 __attribute__((ext_vector_type(4)));
typedef float f32x4 __attribute__((ext_vector_type(4)));
typedef float f32x2 __attribute__((ext_vector_type(2)));

__device__ __forceinline__ float grp_reduce16(float v) {
  v += __shfl_xor(v, 1);
  v += __shfl_xor(v, 2);
  v += __shfl_xor(v, 4);
  v += __shfl_xor(v, 8);
  return v;
}

// LDS pad: +4 floats per 32 (keeps 16B alignment, rotates bank groups)
__device__ __forceinline__ int hpad(int k) { return k + 4 * (k >> 5); }

// device-scope 16B store (write through to coherent point)
__device__ __forceinline__ void st16_sys(u64* p, u32x4 v) {
  asm volatile("global_store_dwordx4 %0, %1, off sc0 sc1" :: "v"(p), "v"(v) : "memory");
}

// Re-init every call (harness does not re-poison d_ws between graph replays).
__global__ void init_comm(u64* __restrict__ comm, const float* __restrict__ h0) {
  int jj = threadIdx.x;                      // 0..511
  u32 bits = __float_as_uint(h0[jj]);
  comm[jj]       = (u64)bits;                // buf0: tag 0 | h0 value
  comm[HSZ + jj] = 0xFFFFFFFF00000000ull;    // buf1: invalid tag
}

__launch_bounds__(TPB, 2)
__global__ void gru_persistent(const float* __restrict__ input,
                               const float* __restrict__ w_ih,
                               const float* __restrict__ w_hh,
                               const float* __restrict__ bias,
                               const float* __restrict__ bias_n,
                               u64* __restrict__ comm,
                               float* __restrict__ out)
{
  const int tid = threadIdx.x;
  const int wg  = blockIdx.x;
  const int g   = tid >> 4;          // 0..31 owned row within WG
  const int l   = tid & 15;          // 0..15 lane within group
  const int laneid = tid & 63;
  const int j   = wg * SWG + g;      // owned global h index

  // ---- one-time: weights into registers (pinned in-loop below) ----
  f32x4 whh[3][8];   // w_hh rows {j, j+512, j+1024}, k in [l*32, l*32+32)
  f32x4 wih[3][4];   // w_ih same rows, k in [l*16, l*16+16)
  #pragma unroll
  for (int q = 0; q < 3; ++q) {
    const float* rp = w_hh + (size_t)(j + 512 * q) * HSZ + l * 32;
    #pragma unroll
    for (int c = 0; c < 8; ++c) whh[q][c] = *(const f32x4*)(rp + c * 4);
    const float* rp2 = w_ih + (size_t)(j + 512 * q) * INSZ + l * 16;
    #pragma unroll
    for (int c = 0; c < 4; ++c) wih[q][c] = *(const f32x4*)(rp2 + c * 4);
  }
  const float b_r = bias[j], b_z = bias[j + 512], b_n = bias[j + 1024];
  const float bn2 = bias_n[j];

  __shared__ float h_lds[2][HSZ + 4 * (HSZ >> 5)];

  // ---- igates for step 0 ----
  float ig0, ig1, ig2;
  {
    const float* ip = input + l * 16;
    float a0 = 0.f, a1 = 0.f, a2 = 0.f;
    #pragma unroll
    for (int c = 0; c < 4; ++c) {
      f32x4 xv = *(const f32x4*)(ip + c * 4);
      #pragma unroll
      for (int u = 0; u < 4; ++u) {
        a0 += wih[0][c][u] * xv[u];
        a1 += wih[1][c][u] * xv[u];
        a2 += wih[2][c][u] * xv[u];
      }
    }
    ig0 = grp_reduce16(a0); ig1 = grp_reduce16(a1); ig2 = grp_reduce16(a2);
  }

#define ISSUE(R) \
  asm volatile("global_load_dwordx4 %0, %1, off sc0 sc1" : "=&v"(R) : "v"(lp) : "memory")
#define CHECK(R) \
  asm volatile("s_waitcnt vmcnt(3)" : "+v"(R)); \
  __builtin_amdgcn_sched_barrier(0); \
  if ((R[1] == tt && R[3] == tt) || --guard == 0) { win = R; break; } \
  ISSUE(R)

  for (int t = 0; t < T_STEPS; ++t) {
    // ---- pin weights live-through (two asm blocks; forbids remat/reload) ----
    asm volatile("" :
      "+v"(whh[0][0]), "+v"(whh[0][1]), "+v"(whh[0][2]), "+v"(whh[0][3]),
      "+v"(whh[0][4]), "+v"(whh[0][5]), "+v"(whh[0][6]), "+v"(whh[0][7]),
      "+v"(whh[1][0]), "+v"(whh[1][1]), "+v"(whh[1][2]), "+v"(whh[1][3]),
      "+v"(whh[1][4]), "+v"(whh[1][5]), "+v"(whh[1][6]), "+v"(whh[1][7]),
      "+v"(whh[2][0]), "+v"(whh[2][1]), "+v"(whh[2][2]), "+v"(whh[2][3]),
      "+v"(whh[2][4]), "+v"(whh[2][5]), "+v"(whh[2][6]), "+v"(whh[2][7]));
    asm volatile("" :
      "+v"(wih[0][0]), "+v"(wih[0][1]), "+v"(wih[0][2]), "+v"(wih[0][3]),
      "+v"(wih[1][0]), "+v"(wih[1][1]), "+v"(wih[1][2]), "+v"(wih[1][3]),
      "+v"(wih[2][0]), "+v"(wih[2][1]), "+v"(wih[2][2]), "+v"(wih[2][3]));

    const int p  = t & 1;
    const u32 tt = (u32)t;

    // ---- poll h_t: threads 0..255 own one 16B line; 4-deep pipelined ----
    if (tid < 256) {
      const u64* lp = comm + (size_t)p * HSZ + 2 * tid;
      u32x4 a, b, c, d, win;
      // isolate poll ring from any outstanding stores/loads (vmcnt discipline)
      asm volatile("s_waitcnt vmcnt(0)" ::: "memory");
      ISSUE(a); ISSUE(b); ISSUE(c); ISSUE(d);
      int guard = POLL_GUARD;
      for (;;) {
        CHECK(a);
        CHECK(b);
        CHECK(c);
        CHECK(d);
      }
      // drain in-flight loads; keep a..d alive so regalloc can't reuse early
      asm volatile("s_waitcnt vmcnt(0)" : "+v"(a), "+v"(b), "+v"(c), "+v"(d));
      __builtin_amdgcn_sched_barrier(0);
      f32x2 hv2;
      hv2[0] = __uint_as_float(win[0]);
      hv2[1] = __uint_as_float(win[2]);
      *(f32x2*)&h_lds[p][hpad(2 * tid)] = hv2;   // 2tid even: same chunk, 8B-aligned
    }
    __syncthreads();

    // ---- prefetch next input row (consumed in igates below) ----
    const int tn = (t + 1 < T_STEPS) ? (t + 1) : (T_STEPS - 1);
    const float* ipn = input + (size_t)tn * INSZ + l * 16;
    f32x4 nv0 = *(const f32x4*)(ipn + 0);
    f32x4 nv1 = *(const f32x4*)(ipn + 4);
    f32x4 nv2 = *(const f32x4*)(ipn + 8);
    f32x4 nv3 = *(const f32x4*)(ipn + 12);

    // ---- hh matvec (critical path): 96 FMA from pinned whh ----
    float hr = 0.f, hz = 0.f, hn = 0.f;
    const float* hp = &h_lds[p][l * 36];   // hpad(l*32)
    #pragma unroll
    for (int c = 0; c < 8; ++c) {
      f32x4 hv = *(const f32x4*)(hp + c * 4);
      #pragma unroll
      for (int u = 0; u < 4; ++u) {
        hr += whh[0][c][u] * hv[u];
        hz += whh[1][c][u] * hv[u];
        hn += whh[2][c][u] * hv[u];
      }
    }
    hr = grp_reduce16(hr); hz = grp_reduce16(hz); hn = grp_reduce16(hn);

    // ---- gates (round-1-proven math) ----
    const float reset = 1.0f / (1.0f + __expf(-(ig0 + b_r + hr)));
    const float upd   = 1.0f / (1.0f + __expf(-(ig1 + b_z + hz)));
    const float hold  = h_lds[p][hpad(j)];
    const float newv  = tanhf(ig2 + b_n + reset * (hn + bn2));
    const float hnew  = newv + upd * (hold - newv);

    // ---- broadcast: 2 tagged words per 16B line (one store per even group) ----
    const float hpart = __shfl(hnew, (laneid + 16) & 63);  // value of group g+1
    if (l == 0 && (g & 1) == 0) {
      u64* nbuf = comm + (size_t)((t + 1) & 1) * HSZ;
      u32x4 pk;
      pk[0] = __float_as_uint(hnew);  pk[1] = (u32)(t + 1);
      pk[2] = __float_as_uint(hpart); pk[3] = (u32)(t + 1);
      st16_sys(&nbuf[j], pk);
      if (j == 0) out[t] = hnew;
    }

    // ---- igates for t+1 (pinned wih: short tail before next poll) ----
    {
      float a0 = 0.f, a1 = 0.f, a2 = 0.f;
      #pragma unroll
      for (int c = 0; c < 4; ++c) {
        f32x4 xv = (c == 0) ? nv0 : ((c == 1) ? nv1 : ((c == 2) ? nv2 : nv3));
        #pragma unroll
        for (int u = 0; u < 4; ++u) {
          a0 += wih[0][c][u] * xv[u];
          a1 += wih[1][c][u] * xv[u];
          a2 += wih[2][c][u] * xv[u];
        }
      }
      ig0 = grp_reduce16(a0); ig1 = grp_reduce16(a1); ig2 = grp_reduce16(a2);
    }
    // no end barrier: h_lds is parity-indexed; the step-t barrier orders reuse
  }
#undef ISSUE
#undef CHECK
}

extern "C" void kernel_launch(void* const* d_in, const int* in_sizes, int n_in,
                              void* d_out, int out_size, void* d_ws, size_t ws_size,
                              hipStream_t stream) {
  const float* input  = (const float*)d_in[0];
  const float* h0     = (const float*)d_in[1];
  const float* w_ih   = (const float*)d_in[2];
  const float* w_hh   = (const float*)d_in[3];
  const float* bias   = (const float*)d_in[4];
  const float* bias_n = (const float*)d_in[5];
  float* out = (float*)d_out;
  u64* comm  = (u64*)d_ws;   // 2 * 512 * 8B = 8 KB

  hipLaunchKernelGGL(init_comm, dim3(1), dim3(HSZ), 0, stream, comm, h0);
  hipLaunchKernelGGL(gru_persistent, dim3(NWG), dim3(TPB), 0, stream,
                     input, w_ih, w_hh, bias, bias_n, comm, out);
}

// Round 6
// 57907.727 us; speedup vs baseline: 1.3819x; 1.0822x over previous
//
#include <hip/hip_runtime.h>

// GRU persistent kernel, round 6: role-partitioned VMEM + structural residency.
// - 32 WGs x 768 threads. thread = (gate-row g in [0,48), k-lane l in [0,16)).
//   g 0..15 -> reset rows, 16..31 -> update rows, 32..47 -> newgate rows.
//   Per-thread weights = 48 f32 (whh 8 quads + wih 4 quads): small enough that
//   the compiler keeps them register-resident naturally (rounds 1/3/5: asm
//   pinning of 144 f32 only produced scratch spills at VGPR=104).
// - VMEM role separation (round-5 bug fix): comm stores only on tid<16;
//   POLLERS are tid 256..511 with no other VMEM ever -> no vmcnt(0) preamble,
//   no store-ack serialized into the poll path; poll-ring leftovers stay in
//   flight across steps (wrong-parity tags rejected; FIFO vmcnt + dedicated
//   ring registers make reg reuse benign).
// - Input rows staged to LDS by tid 512..575 -> igates phase is LDS-only.
// - h broadcast: tagged 8B words {val|step}, 2 per 16B line, double-buffered
//   by parity (round-1-proven). 2 barriers/step. isum parity-double-buffered.
// - No placement protocol; poll guard -> fast wrong-answer, never a hang.

#define T_STEPS    32768
#define INSZ       256
#define HSZ        512
#define TPB        768
#define NWG        32
#define POLL_GUARD 16384

typedef unsigned long long u64;
typedef unsigned int u32;
typedef u32 u32x4 __attribute__((ext_vector_type(4)));
typedef float f32x4 __attribute__((ext_vector_type(4)));
typedef float f32x2 __attribute__((ext_vector_type(2)));

__device__ __forceinline__ float grp_reduce16(float v) {
  v += __shfl_xor(v, 1);
  v += __shfl_xor(v, 2);
  v += __shfl_xor(v, 4);
  v += __shfl_xor(v, 8);
  return v;
}

// LDS pad: +4 floats per 32 (keeps 16B alignment, rotates bank groups)
__device__ __forceinline__ int hpad(int k) { return k + 4 * (k >> 5); }

__device__ __forceinline__ void st16_sys(u64* p, u32x4 v) {
  asm volatile("global_store_dwordx4 %0, %1, off sc0 sc1" :: "v"(p), "v"(v) : "memory");
}

// Re-init every call (harness does not re-poison d_ws between graph replays).
__global__ void init_comm(u64* __restrict__ comm, const float* __restrict__ h0) {
  int jj = threadIdx.x;                      // 0..511
  u32 bits = __float_as_uint(h0[jj]);
  comm[jj]       = (u64)bits;                // buf0: tag 0 | h0 value
  comm[HSZ + jj] = 0xFFFFFFFF00000000ull;    // buf1: invalid tag
}

__launch_bounds__(TPB, 1)
__global__ void gru_persistent(const float* __restrict__ input,
                               const float* __restrict__ init_hidden,
                               const float* __restrict__ w_ih,
                               const float* __restrict__ w_hh,
                               const float* __restrict__ bias,
                               const float* __restrict__ bias_n,
                               u64* __restrict__ comm,
                               float* __restrict__ out)
{
  const int tid = threadIdx.x;
  const int wg  = blockIdx.x;
  const int g   = tid >> 4;                             // gate-row 0..47
  const int l   = tid & 15;                             // k-lane 0..15
  const int R   = wg * 16 + (g & 15) + 512 * (g >> 4);  // global gate row

  // ---- weights: 48 f32/thread, compiler-resident ----
  f32x4 whh[8];   // w_hh row R, k in [l*32, l*32+32)
  f32x4 wih[4];   // w_ih row R, k in [l*16, l*16+16)
  {
    const float* rp = w_hh + (size_t)R * HSZ + l * 32;
    #pragma unroll
    for (int c = 0; c < 8; ++c) whh[c] = *(const f32x4*)(rp + c * 4);
    const float* rp2 = w_ih + (size_t)R * INSZ + l * 16;
    #pragma unroll
    for (int c = 0; c < 4; ++c) wih[c] = *(const f32x4*)(rp2 + c * 4);
  }

  // ---- gate-thread state (tid<16): h_prev + biases for row wg*16+tid ----
  float hold = 0.f, b_r = 0.f, b_z = 0.f, b_n = 0.f, bn = 0.f;
  if (tid < 16) {
    const int j = wg * 16 + tid;
    hold = init_hidden[j];
    b_r  = bias[j];
    b_z  = bias[j + 512];
    b_n  = bias[j + 1024];
    bn   = bias_n[j];
  }

  __shared__ float h_lds[2][HSZ + 4 * (HSZ >> 5)];
  __shared__ float gsum[48];
  __shared__ float isum[2][48];
  __shared__ float xstage[INSZ];

  // ---- stage x(0) and compute igates(0) ----
  if (tid < 64) {
    f32x4 v = *(const f32x4*)(input + tid * 4);
    *(f32x4*)&xstage[tid * 4] = v;
  }
  __syncthreads();
  {
    float a = 0.f;
    #pragma unroll
    for (int c = 0; c < 4; ++c) {
      f32x4 xv = *(const f32x4*)&xstage[l * 16 + c * 4];
      #pragma unroll
      for (int u = 0; u < 4; ++u) a += wih[c][u] * xv[u];
    }
    a = grp_reduce16(a);
    if (l == 0) isum[0][g] = a;
  }

  const int poller = (tid >= 256 && tid < 512);
  const int pt     = tid - 256;
  const int stager = (tid >= 512 && tid < 576);
  u32x4 pa, pb, pc, pd, win;

#define ISSUE(Rr) \
  asm volatile("global_load_dwordx4 %0, %1, off sc0 sc1" : "=&v"(Rr) : "v"(lp) : "memory")
#define CHECK(Rr) \
  asm volatile("s_waitcnt vmcnt(3)" : "+v"(Rr)); \
  __builtin_amdgcn_sched_barrier(0); \
  if ((Rr[1] == tt && Rr[3] == tt) || --guard == 0) { win = Rr; break; } \
  ISSUE(Rr)

  for (int t = 0; t < T_STEPS; ++t) {
    const int p  = t & 1;
    const u32 tt = (u32)t;

    // ---- poll h_t (pollers only; vmcnt queue holds ONLY poll loads) ----
    if (poller) {
      const u64* lp = comm + (size_t)p * HSZ + 2 * pt;
      ISSUE(pa); ISSUE(pb); ISSUE(pc); ISSUE(pd);
      int guard = POLL_GUARD;
      for (;;) {
        CHECK(pa);
        CHECK(pb);
        CHECK(pc);
        CHECK(pd);
      }
      f32x2 hv;
      hv[0] = __uint_as_float(win[0]);
      hv[1] = __uint_as_float(win[2]);
      *(f32x2*)&h_lds[p][hpad(2 * pt)] = hv;
    }
    // ---- stagers: issue x(t+1) loads early (landing hidden under matvec) ----
    f32x4 xnew = {0.f, 0.f, 0.f, 0.f};
    if (stager) {
      const int tn = (t + 1 < T_STEPS) ? (t + 1) : (T_STEPS - 1);
      xnew = *(const f32x4*)(input + (size_t)tn * INSZ + (tid - 512) * 4);
    }
    __syncthreads();   // sync1: h_lds[p] complete

    // ---- hh matvec: each thread 32 MAC on its k-chunk of its gate-row ----
    float a = 0.f;
    {
      const float* hp = &h_lds[p][l * 36];   // hpad(l*32)
      #pragma unroll
      for (int c = 0; c < 8; ++c) {
        f32x4 hv4 = *(const f32x4*)(hp + c * 4);
        #pragma unroll
        for (int u = 0; u < 4; ++u) a += whh[c][u] * hv4[u];
      }
    }
    a = grp_reduce16(a);
    if (l == 0) gsum[g] = a;
    if (stager) *(f32x4*)&xstage[(tid - 512) * 4] = xnew;
    __syncthreads();   // sync2: gsum + xstage ready

    // ---- gates + broadcast (tid<16 only; the ONLY comm-store threads) ----
    if (tid < 16) {
      const int j = tid;
      const float hr = gsum[j], hz = gsum[16 + j], hn = gsum[32 + j];
      const float i_r = isum[p][j], i_z = isum[p][16 + j], i_n = isum[p][32 + j];
      const float reset = 1.0f / (1.0f + __expf(-(i_r + b_r + hr)));
      const float upd   = 1.0f / (1.0f + __expf(-(i_z + b_z + hz)));
      const float newv  = tanhf(i_n + b_n + reset * (hn + bn));
      const float hnew  = newv + upd * (hold - newv);
      hold = hnew;
      const float hpair = __shfl(hnew, tid + 1);   // partner row's value
      if ((j & 1) == 0) {
        u64* nbuf = comm + (size_t)((t + 1) & 1) * HSZ;
        u32x4 pk;
        pk[0] = __float_as_uint(hnew);  pk[1] = (u32)(t + 1);
        pk[2] = __float_as_uint(hpair); pk[3] = (u32)(t + 1);
        st16_sys(&nbuf[wg * 16 + j], pk);
        if (wg == 0 && j == 0) out[t] = hnew;
      }
    }

    // ---- igates(t+1) from LDS-staged x(t+1) (no VMEM) ----
    {
      float a2 = 0.f;
      #pragma unroll
      for (int c = 0; c < 4; ++c) {
        f32x4 xv = *(const f32x4*)&xstage[l * 16 + c * 4];
        #pragma unroll
        for (int u = 0; u < 4; ++u) a2 += wih[c][u] * xv[u];
      }
      a2 = grp_reduce16(a2);
      if (l == 0) isum[(t + 1) & 1][g] = a2;
    }
  }
#undef ISSUE
#undef CHECK
}

extern "C" void kernel_launch(void* const* d_in, const int* in_sizes, int n_in,
                              void* d_out, int out_size, void* d_ws, size_t ws_size,
                              hipStream_t stream) {
  const float* input  = (const float*)d_in[0];
  const float* h0     = (const float*)d_in[1];
  const float* w_ih   = (const float*)d_in[2];
  const float* w_hh   = (const float*)d_in[3];
  const float* bias   = (const float*)d_in[4];
  const float* bias_n = (const float*)d_in[5];
  float* out = (float*)d_out;
  u64* comm  = (u64*)d_ws;   // 2 * 512 * 8B = 8 KB

  hipLaunchKernelGGL(init_comm, dim3(1), dim3(HSZ), 0, stream, comm, h0);
  hipLaunchKernelGGL(gru_persistent, dim3(NWG), dim3(TPB), 0, stream,
                     input, h0, w_ih, w_hh, bias, bias_n, comm, out);
}

// Round 7
// 51764.191 us; speedup vs baseline: 1.5459x; 1.1187x over previous
//
#include <hip/hip_runtime.h>

// GRU persistent kernel, round 7.
// Comm protocol identical to round 6 (proven): tagged 8B words {val|step},
// 2 per 16B line, double-buffered by parity, sc0+sc1 stores/polls, 4-deep
// pipelined poll ring (FIFO vmcnt retire makes cross-iteration leftovers safe).
// Changes vs r6, all counter-driven:
//  - TPB 1024: pollers = tid 768..1023 do NOTHING but poll (r6 had pollers
//    running the igates tail with 8-way xstage bank conflicts -> ~500cy of
//    poll-phase delay per step; SQ_LDS_BANK_CONFLICT=6.0e8).
//  - xstage padded (+4 floats per 16): igates reads 2-way max (free).
//  - fast gates: sigmoid/tanh via v_exp + v_rcp (no ocml tanhf).
//  - stagers = tid 64..127 (gate threads' vmcnt queue = only their comm store).

#define T_STEPS    32768
#define INSZ       256
#define HSZ        512
#define TPB        1024
#define NWG        32
#define POLL_GUARD 16384

typedef unsigned long long u64;
typedef unsigned int u32;
typedef u32 u32x4 __attribute__((ext_vector_type(4)));
typedef float f32x4 __attribute__((ext_vector_type(4)));
typedef float f32x2 __attribute__((ext_vector_type(2)));

__device__ __forceinline__ float grp_reduce16(float v) {
  v += __shfl_xor(v, 1);
  v += __shfl_xor(v, 2);
  v += __shfl_xor(v, 4);
  v += __shfl_xor(v, 8);
  return v;
}

// h_lds pad: +4 floats per 32 (keeps 16B alignment; matvec reads are
// broadcast across the 4 groups of a wave and 2-way within -> free)
__device__ __forceinline__ int hpad(int k) { return k + 4 * (k >> 5); }
// xstage pad: +4 floats per 16 (igates reads at 20l+4c -> 2-way max)
__device__ __forceinline__ int xpad(int k) { return k + ((k >> 4) << 2); }

__device__ __forceinline__ void st16_sys(u64* p, u32x4 v) {
  asm volatile("global_store_dwordx4 %0, %1, off sc0 sc1" :: "v"(p), "v"(v) : "memory");
}

// Re-init every call (harness does not re-poison d_ws between graph replays).
__global__ void init_comm(u64* __restrict__ comm, const float* __restrict__ h0) {
  int jj = threadIdx.x;                      // 0..511
  u32 bits = __float_as_uint(h0[jj]);
  comm[jj]       = (u64)bits;                // buf0: tag 0 | h0 value
  comm[HSZ + jj] = 0xFFFFFFFF00000000ull;    // buf1: invalid tag
}

__launch_bounds__(TPB, 1)
__global__ void gru_persistent(const float* __restrict__ input,
                               const float* __restrict__ init_hidden,
                               const float* __restrict__ w_ih,
                               const float* __restrict__ w_hh,
                               const float* __restrict__ bias,
                               const float* __restrict__ bias_n,
                               u64* __restrict__ comm,
                               float* __restrict__ out)
{
  const int tid = threadIdx.x;
  const int wg  = blockIdx.x;
  const int g   = tid >> 4;                             // 0..63
  const int l   = tid & 15;
  const bool mv = (g < 48);                             // matvec/igates threads
  const int R   = wg * 16 + (g & 15) + 512 * (g >> 4);  // valid iff mv

  // ---- weights: 48 f32/thread on mv threads (structurally resident, r6) ----
  f32x4 whh[8];
  f32x4 wih[4];
  if (mv) {
    const float* rp = w_hh + (size_t)R * HSZ + l * 32;
    #pragma unroll
    for (int c = 0; c < 8; ++c) whh[c] = *(const f32x4*)(rp + c * 4);
    const float* rp2 = w_ih + (size_t)R * INSZ + l * 16;
    #pragma unroll
    for (int c = 0; c < 4; ++c) wih[c] = *(const f32x4*)(rp2 + c * 4);
  }

  // ---- gate-thread state (tid<16): h_prev + biases for row wg*16+tid ----
  float hold = 0.f, b_r = 0.f, b_z = 0.f, b_n = 0.f, bn = 0.f;
  if (tid < 16) {
    const int j = wg * 16 + tid;
    hold = init_hidden[j];
    b_r  = bias[j];
    b_z  = bias[j + 512];
    b_n  = bias[j + 1024];
    bn   = bias_n[j];
  }

  __shared__ float h_lds[2][HSZ + 4 * (HSZ >> 5)];
  __shared__ float gsum[48];
  __shared__ float isum[2][48];
  __shared__ float xstage[INSZ + (INSZ >> 4) * 4];

  // ---- stage x(0); igates(0) ----
  if (tid >= 64 && tid < 128) {
    const int s = tid - 64;
    f32x4 v = *(const f32x4*)(input + s * 4);
    *(f32x4*)&xstage[xpad(s * 4)] = v;
  }
  __syncthreads();
  if (mv) {
    float a = 0.f;
    #pragma unroll
    for (int c = 0; c < 4; ++c) {
      f32x4 xv = *(const f32x4*)&xstage[20 * l + 4 * c];   // xpad(16l+4c)
      #pragma unroll
      for (int u = 0; u < 4; ++u) a += wih[c][u] * xv[u];
    }
    a = grp_reduce16(a);
    if (l == 0) isum[0][g] = a;
  }

  const bool poller = (tid >= 768);
  const int  pt     = tid - 768;          // 0..255
  u32x4 pa, pb, pc, pd, win;

#define ISSUE(Rr) \
  asm volatile("global_load_dwordx4 %0, %1, off sc0 sc1" : "=&v"(Rr) : "v"(lp) : "memory")
#define CHECK(Rr) \
  asm volatile("s_waitcnt vmcnt(3)" : "+v"(Rr)); \
  __builtin_amdgcn_sched_barrier(0); \
  if ((Rr[1] == tt && Rr[3] == tt) || --guard == 0) { win = Rr; break; } \
  ISSUE(Rr)

  for (int t = 0; t < T_STEPS; ++t) {
    const int p  = t & 1;
    const u32 tt = (u32)t;

    // ---- stagers: issue x(t+1) loads now (land under poll+matvec) ----
    f32x4 xnew = {0.f, 0.f, 0.f, 0.f};
    if (tid >= 64 && tid < 128) {
      const int tn = (t + 1 < T_STEPS) ? (t + 1) : (T_STEPS - 1);
      xnew = *(const f32x4*)(input + (size_t)tn * INSZ + (tid - 64) * 4);
    }

    // ---- poll h_t (dedicated pollers; vmcnt queue = poll loads only) ----
    if (poller) {
      const u64* lp = comm + (size_t)p * HSZ + 2 * pt;
      ISSUE(pa); ISSUE(pb); ISSUE(pc); ISSUE(pd);
      int guard = POLL_GUARD;
      for (;;) {
        CHECK(pa);
        CHECK(pb);
        CHECK(pc);
        CHECK(pd);
      }
      f32x2 hv;
      hv[0] = __uint_as_float(win[0]);
      hv[1] = __uint_as_float(win[2]);
      *(f32x2*)&h_lds[p][hpad(2 * pt)] = hv;
    }
    __syncthreads();   // sync1: h_lds[p] complete

    // ---- hh matvec: 32 MAC per mv thread on its k-chunk ----
    if (mv) {
      float a = 0.f;
      const float* hp = &h_lds[p][l * 36];   // hpad(32l); broadcast across groups
      #pragma unroll
      for (int c = 0; c < 8; ++c) {
        f32x4 hv4 = *(const f32x4*)(hp + c * 4);
        #pragma unroll
        for (int u = 0; u < 4; ++u) a += whh[c][u] * hv4[u];
      }
      a = grp_reduce16(a);
      if (l == 0) gsum[g] = a;
    }
    if (tid >= 64 && tid < 128) *(f32x4*)&xstage[xpad((tid - 64) * 4)] = xnew;
    __syncthreads();   // sync2: gsum + xstage ready

    // ---- gates + broadcast (tid<16; fast exp/rcp math) ----
    if (tid < 16) {
      const int j = tid;
      const float hr = gsum[j], hz = gsum[16 + j], hn = gsum[32 + j];
      const float i_r = isum[p][j], i_z = isum[p][16 + j], i_n = isum[p][32 + j];
      const float reset = __builtin_amdgcn_rcpf(1.0f + __expf(-(i_r + b_r + hr)));
      const float upd   = __builtin_amdgcn_rcpf(1.0f + __expf(-(i_z + b_z + hz)));
      const float e2    = __expf(2.0f * (i_n + b_n + reset * (hn + bn)));
      const float newv  = 1.0f - 2.0f * __builtin_amdgcn_rcpf(1.0f + e2);
      const float hnew  = newv + upd * (hold - newv);
      hold = hnew;
      const float hpair = __shfl(hnew, tid + 1);
      if ((j & 1) == 0) {
        u64* nbuf = comm + (size_t)((t + 1) & 1) * HSZ;
        u32x4 pk;
        pk[0] = __float_as_uint(hnew);  pk[1] = (u32)(t + 1);
        pk[2] = __float_as_uint(hpair); pk[3] = (u32)(t + 1);
        st16_sys(&nbuf[wg * 16 + j], pk);
        if (wg == 0 && j == 0) out[t] = hnew;
      }
    }

    // ---- igates(t+1) on mv threads only (pollers already polling t+1) ----
    if (mv) {
      float a2 = 0.f;
      #pragma unroll
      for (int c = 0; c < 4; ++c) {
        f32x4 xv = *(const f32x4*)&xstage[20 * l + 4 * c];
        #pragma unroll
        for (int u = 0; u < 4; ++u) a2 += wih[c][u] * xv[u];
      }
      a2 = grp_reduce16(a2);
      if (l == 0) isum[(t + 1) & 1][g] = a2;
    }
  }
#undef ISSUE
#undef CHECK
}

extern "C" void kernel_launch(void* const* d_in, const int* in_sizes, int n_in,
                              void* d_out, int out_size, void* d_ws, size_t ws_size,
                              hipStream_t stream) {
  const float* input  = (const float*)d_in[0];
  const float* h0     = (const float*)d_in[1];
  const float* w_ih   = (const float*)d_in[2];
  const float* w_hh   = (const float*)d_in[3];
  const float* bias   = (const float*)d_in[4];
  const float* bias_n = (const float*)d_in[5];
  float* out = (float*)d_out;
  u64* comm  = (u64*)d_ws;   // 2 * 512 * 8B = 8 KB

  hipLaunchKernelGGL(init_comm, dim3(1), dim3(HSZ), 0, stream, comm, h0);
  hipLaunchKernelGGL(gru_persistent, dim3(NWG), dim3(TPB), 0, stream,
                     input, h0, w_ih, w_hh, bias, bias_n, comm, out);
}